// Round 11
// baseline (3167.652 us; speedup 1.0000x reference)
//
#include <hip/hip_runtime.h>
#include <hip/hip_bf16.h>

#define B_   64
#define T_   1024
#define IND_ 256
#define U_   512
#define G3_  1536
#define BPG   8     // fallback: batches per group
#define SLOTS 32    // fallback: WGs per group

typedef unsigned int u32;
typedef unsigned short u16;
typedef unsigned long long u64;
typedef __attribute__((ext_vector_type(8))) short short8;
typedef __attribute__((ext_vector_type(4))) float f32x4;
typedef __attribute__((ext_vector_type(4))) unsigned int u32x4;

union S8 { short8 v; u16 us[8]; u32 d[4]; u64 q[2]; };
union BF { __hip_bfloat16 b; u16 u; };
union FU { float f; u32 u; };

__device__ __forceinline__ u16 f2b(float f){ BF t; t.b = __float2bfloat16(f); return t.u; }
__device__ __forceinline__ float b2f(u16 u){ FU t; t.u = ((u32)u) << 16; return t.f; }
__device__ __forceinline__ float hsig(float a){ return fminf(fmaxf(fmaf(a, 0.2f, 0.5f), 0.f), 1.f); }
__device__ __forceinline__ u32 umax2(u32 a, u32 b){ return a > b ? a : b; }
__device__ __forceinline__ float fast_tanh(float x){
  float ax = fabsf(x);
  float e  = __expf(ax + ax);
  float r  = 1.f - 2.f / (e + 1.f);
  return copysignf(r, x);
}
__device__ __forceinline__ void drain_vm(){
  asm volatile("s_waitcnt vmcnt(0)" ::: "memory");
  __builtin_amdgcn_sched_barrier(0);
}
__device__ __forceinline__ void st_sys(u32* p, u32 v){
  asm volatile("global_store_dword %0, %1, off sc0 sc1" :: "v"(p), "v"(v) : "memory");
}
__device__ __forceinline__ u32 ld_sys(const u32* p){
  u32 v;
  asm volatile("global_load_dword %0, %1, off sc0 sc1\n\ts_waitcnt vmcnt(0)"
               : "=v"(v) : "v"(p) : "memory");
  return v;
}

// batched A-fragment load: 16 x 16B, device-coherent, ONE wait
#define LDA16(aa, hb) \
  asm volatile( \
    "global_load_dwordx4 %0,  %16, off sc0 sc1\n\t" \
    "global_load_dwordx4 %1,  %16, off offset:64 sc0 sc1\n\t" \
    "global_load_dwordx4 %2,  %16, off offset:128 sc0 sc1\n\t" \
    "global_load_dwordx4 %3,  %16, off offset:192 sc0 sc1\n\t" \
    "global_load_dwordx4 %4,  %16, off offset:256 sc0 sc1\n\t" \
    "global_load_dwordx4 %5,  %16, off offset:320 sc0 sc1\n\t" \
    "global_load_dwordx4 %6,  %16, off offset:384 sc0 sc1\n\t" \
    "global_load_dwordx4 %7,  %16, off offset:448 sc0 sc1\n\t" \
    "global_load_dwordx4 %8,  %16, off offset:512 sc0 sc1\n\t" \
    "global_load_dwordx4 %9,  %16, off offset:576 sc0 sc1\n\t" \
    "global_load_dwordx4 %10, %16, off offset:640 sc0 sc1\n\t" \
    "global_load_dwordx4 %11, %16, off offset:704 sc0 sc1\n\t" \
    "global_load_dwordx4 %12, %16, off offset:768 sc0 sc1\n\t" \
    "global_load_dwordx4 %13, %16, off offset:832 sc0 sc1\n\t" \
    "global_load_dwordx4 %14, %16, off offset:896 sc0 sc1\n\t" \
    "global_load_dwordx4 %15, %16, off offset:960 sc0 sc1\n\t" \
    "s_waitcnt vmcnt(0)" \
    : "=&v"(aa[0].v),  "=&v"(aa[1].v),  "=&v"(aa[2].v),  "=&v"(aa[3].v), \
      "=&v"(aa[4].v),  "=&v"(aa[5].v),  "=&v"(aa[6].v),  "=&v"(aa[7].v), \
      "=&v"(aa[8].v),  "=&v"(aa[9].v),  "=&v"(aa[10].v), "=&v"(aa[11].v), \
      "=&v"(aa[12].v), "=&v"(aa[13].v), "=&v"(aa[14].v), "=&v"(aa[15].v) \
    : "v"(hb) : "memory")

// ---------------- prep kernels ----------------

__global__ void k_zero(u32* c) {
  int i = threadIdx.x;
  for (int k = i; k < 1024; k += 256) c[k] = 0u;
}

__global__ void k_fill(u32x4* p) {   // sentinel fill
  size_t i = (size_t)blockIdx.x * 256 + threadIdx.x;
  u32x4 v = {0xFFFFFFFFu, 0xFFFFFFFFu, 0xFFFFFFFFu, 0xFFFFFFFFu};
  p[i] = v;
}

__global__ void k_wt(const float* __restrict__ rk, const float* __restrict__ xk,
                     u16* __restrict__ WrT, u16* __restrict__ WxT) {
  int i = blockIdx.x * 256 + threadIdx.x;
  if (i < U_ * G3_) {
    int k = i / G3_, c = i - k * G3_;
    WrT[(size_t)c * U_ + k] = f2b(rk[i]);
  } else {
    int j = i - U_ * G3_;
    int k = j / G3_, c = j - k * G3_;
    WxT[(size_t)c * IND_ + k] = f2b(xk[j]);
  }
}

__global__ void k_xb(const float* __restrict__ x, u16* __restrict__ xb) {
  size_t i = ((size_t)blockIdx.x * 256 + threadIdx.x) * 8;
  const float4* p = (const float4*)(x + i);
  float4 a = p[0], b = p[1];
  S8 o;
  o.us[0]=f2b(a.x); o.us[1]=f2b(a.y); o.us[2]=f2b(a.z); o.us[3]=f2b(a.w);
  o.us[4]=f2b(b.x); o.us[5]=f2b(b.y); o.us[6]=f2b(b.z); o.us[7]=f2b(b.w);
  *(short8*)(xb + i) = o.v;
}

__global__ void k_pp(const float* __restrict__ peak, const float* __restrict__ pk,
                     float* __restrict__ pp) {
  int i = blockIdx.x * 256 + threadIdx.x;   // 64*1536
  int b = i / G3_, c = i - b * G3_;
  const float* pr = peak + b * U_;
  float s = 0.f;
  for (int k = 0; k < U_; ++k) s = fmaf(pr[k], pk[(size_t)k * G3_ + c], s);
  pp[i] = s;
}

// primary: h0 -> bf16 directly into hbuf slice 0
__global__ void k_h0b(const float* __restrict__ peak, const float* __restrict__ pi,
                      u16* __restrict__ hb0) {
  int i = blockIdx.x * 256 + threadIdx.x;   // 64*512
  int b = i >> 9, u = i & 511;
  const float* pr = peak + b * U_;
  float s = 0.f;
  for (int k = 0; k < U_; ++k) s = fmaf(pr[k], pi[(size_t)k * U_ + u], s);
  hb0[i] = f2b(s);
}

// fallback: f32 h0 + bf16 copy
__global__ void k_h0(const float* __restrict__ peak, const float* __restrict__ pi,
                     float* __restrict__ h0, u16* __restrict__ hb0) {
  int i = blockIdx.x * 256 + threadIdx.x;
  int b = i >> 9, u = i & 511;
  const float* pr = peak + b * U_;
  float s = 0.f;
  for (int k = 0; k < U_; ++k) s = fmaf(pr[k], pi[(size_t)k * U_ + u], s);
  h0[i] = s;
  hb0[i] = f2b(s);
}

// out[b][t][u] = f32(hbuf[t+1][b][u]) — pure bandwidth
__global__ void k_out(const u16* __restrict__ hbuf, float* __restrict__ out) {
  size_t i = ((size_t)blockIdx.x * 256 + threadIdx.x) * 8;   // out linear idx
  size_t b = i >> 19;
  size_t r = i & 524287;
  size_t t = r >> 9;
  size_t u = r & 511;
  S8 v;
  v.v = *(const short8*)(hbuf + (t + 1) * (size_t)(B_ * U_) + b * U_ + u);
  float4 o0, o1;
  o0.x = b2f(v.us[0]); o0.y = b2f(v.us[1]); o0.z = b2f(v.us[2]); o0.w = b2f(v.us[3]);
  o1.x = b2f(v.us[4]); o1.y = b2f(v.us[5]); o1.z = b2f(v.us[6]); o1.w = b2f(v.us[7]);
  float4* dst = (float4*)(out + i);
  dst[0] = o0;
  dst[1] = o1;
}

// ---------------- SENT scan: sentinel dataflow (round-10 + congestion fixes) ----------------
// 128 one-wave WGs. Group g = bid&3 owns batches [16g,16g+16); slot s = bid>>2
// owns h-columns [16s,16s+16). hbuf = [1025][64][512] bf16 sentinel-prefilled.
// Round-11 deltas vs round 10: (1) 16B packed publish (4x fewer MALL store
// transactions, frag-atomic); (2) s_sleep(1) back-off on failed poll (stops
// MALL hammering); (3) group phase-stagger at start (~512g cy) so the four
// groups' poll bursts interleave instead of stacking.

template<bool XBQ>
__global__ __launch_bounds__(64, 1) void k_scan_s(
    const void* __restrict__ xsrc, const float* __restrict__ bias,
    const float* __restrict__ pp,
    const u16* __restrict__ WrT, const u16* __restrict__ WxT,
    u16* __restrict__ hbuf)
{
  __shared__ short8 lB[4608];   // [0,3072): Wr frag-linear; [3072,4608): Wx

  const int tid = threadIdx.x;
  const int g = blockIdx.x & 3;
  const int s = blockIdx.x >> 2;
  const int scol0 = s * 16;

  for (int lin = tid; lin < 3072; lin += 64) {
    int lp = lin & 63, ks = (lin >> 6) & 15, gate = lin >> 10;
    int cc = lp & 15, kk = lp >> 4;
    lB[lin] = *(const short8*)(WrT + (size_t)(gate * U_ + scol0 + cc) * U_ + ks * 32 + kk * 8);
  }
  for (int lin = tid; lin < 1536; lin += 64) {
    int lp = lin & 63, ks = (lin >> 6) & 7, gate = lin >> 9;
    int cc = lp & 15, kk = lp >> 4;
    lB[3072 + lin] = *(const short8*)(WxT + (size_t)(gate * U_ + scol0 + cc) * IND_ + ks * 32 + kk * 8);
  }
  __syncthreads();

  // group phase-stagger: offset poll bursts of the 4 independent chains
  for (int i = 0; i < g; ++i) __builtin_amdgcn_s_sleep(8);

  const int c   = tid & 15;
  const int kg  = tid >> 4;
  const int col = scol0 + c;

  float bpz[4], bpr[4], pph[4], hprev[4];
  float bh = bias[2 * U_ + col];
#pragma unroll
  for (int q = 0; q < 4; ++q) {
    int bg = g * 16 + kg * 4 + q;
    bpz[q]   = bias[col]       + pp[(size_t)bg * G3_ + col];
    bpr[q]   = bias[U_ + col]  + pp[(size_t)bg * G3_ + U_ + col];
    pph[q]   = pp[(size_t)bg * G3_ + 2 * U_ + col];
    hprev[q] = b2f(hbuf[(size_t)bg * U_ + col]);   // slice 0 = h0 (bf16)
  }

  const u16*   xbrow = (const u16*)xsrc   + (size_t)(g * 16 + c) * T_ * IND_;
  const float* xfrow = (const float*)xsrc + (size_t)(g * 16 + c) * T_ * IND_;
  const f32x4 z4 = {0.f, 0.f, 0.f, 0.f};
  f32x4 pxz, pxr, pxh;
  S8 xaA[8], xaB[8];

#define XLOAD(tt, XA) do { \
    if constexpr (XBQ) { \
      _Pragma("unroll") \
      for (int ks = 0; ks < 8; ++ks) \
        XA[ks].v = *(const short8*)(xbrow + (size_t)(tt) * IND_ + kg * 8 + ks * 32); \
    } else { \
      _Pragma("unroll") \
      for (int ks = 0; ks < 8; ++ks) { \
        const float4* p4_ = (const float4*)(xfrow + (size_t)(tt) * IND_ + kg * 8 + ks * 32); \
        float4 x0_ = p4_[0], x1_ = p4_[1]; \
        XA[ks].us[0]=f2b(x0_.x); XA[ks].us[1]=f2b(x0_.y); XA[ks].us[2]=f2b(x0_.z); XA[ks].us[3]=f2b(x0_.w); \
        XA[ks].us[4]=f2b(x1_.x); XA[ks].us[5]=f2b(x1_.y); XA[ks].us[6]=f2b(x1_.z); XA[ks].us[7]=f2b(x1_.w); \
      } \
    } \
  } while (0)

#define XMFMA(XA) do { \
    _Pragma("unroll") \
    for (int ks = 0; ks < 8; ++ks) { \
      pxz = __builtin_amdgcn_mfma_f32_16x16x32_bf16(XA[ks].v, lB[3072 + (0*8+ks)*64 + tid], pxz, 0,0,0); \
      pxr = __builtin_amdgcn_mfma_f32_16x16x32_bf16(XA[ks].v, lB[3072 + (1*8+ks)*64 + tid], pxr, 0,0,0); \
      pxh = __builtin_amdgcn_mfma_f32_16x16x32_bf16(XA[ks].v, lB[3072 + (2*8+ks)*64 + tid], pxh, 0,0,0); \
    } \
  } while (0)

  // prologue: XGEMM(0) ready before first poll; x(1) in flight in xaA
  XLOAD(0, xaB);
  pxz = z4; pxr = z4; pxh = z4;
  XMFMA(xaB);
  XLOAD(1, xaA);

// one timestep. XCN = x(t+1) regs (consumed by XMFMA at end);
// XLD = buffer receiving x(t+2) (issued right after poll success).
#define ONESTEP(t, XCN, XLD) do { \
    const u16* hb = hbuf + (size_t)(t) * (B_ * U_) + (size_t)(g * 16 + c) * U_ + kg * 8; \
    S8 aa[16]; \
    for (;;) { \
      LDA16(aa, hb); \
      u32 mx = 0; \
      _Pragma("unroll") \
      for (int ks = 0; ks < 16; ++ks) \
        mx = umax2(mx, umax2(umax2(aa[ks].d[0], aa[ks].d[1]), \
                             umax2(aa[ks].d[2], aa[ks].d[3]))); \
      if (__all((int)(mx < 0xFFFF0000u))) break; \
      __builtin_amdgcn_s_sleep(1);               /* back-off: stop MALL hammering */ \
    } \
    if ((t) + 2 < T_) XLOAD((t) + 2, XLD);       /* ~1.5 steps of flight */ \
    f32x4 az = pxz, ar = pxr, ah = pxh, ahr = z4; \
    _Pragma("unroll") \
    for (int ks = 0; ks < 16; ++ks) { \
      az  = __builtin_amdgcn_mfma_f32_16x16x32_bf16(aa[ks].v, lB[(0*16+ks)*64 + tid], az,  0,0,0); \
      ar  = __builtin_amdgcn_mfma_f32_16x16x32_bf16(aa[ks].v, lB[(1*16+ks)*64 + tid], ar,  0,0,0); \
      ahr = __builtin_amdgcn_mfma_f32_16x16x32_bf16(aa[ks].v, lB[(2*16+ks)*64 + tid], ahr, 0,0,0); \
    } \
    float hnew[4]; \
    _Pragma("unroll") \
    for (int q = 0; q < 4; ++q) { \
      float z  = hsig(az[q] + bpz[q]); \
      float r  = hsig(ar[q] + bpr[q]); \
      float hh = fast_tanh(ah[q] + bh + r * (ahr[q] + pph[q])); \
      hnew[q] = fmaf(z, hprev[q] - hh, hh); \
      hprev[q] = hnew[q]; \
    } \
    u16* hb1 = hbuf + (size_t)((t) + 1) * (B_ * U_); \
    _Pragma("unroll") \
    for (int q = 0; q < 4; ++q) { \
      u32 hv = (u32)f2b(hnew[q]); \
      u32 w0 = hv | ((u32)__shfl_xor((int)hv, 1) << 16); \
      u32 w1 = (u32)__shfl_xor((int)w0, 2); \
      u32 w2 = (u32)__shfl_xor((int)w0, 4); \
      u32 w3 = (u32)__shfl_xor((int)w1, 4); \
      if (!(c & 7)) { \
        u32x4 vv = {w0, w1, w2, w3}; \
        asm volatile("global_store_dwordx4 %0, %1, off sc0 sc1" \
                     :: "v"((u32*)(hb1 + (size_t)(g * 16 + kg * 4 + q) * U_ + scol0 + c)), "v"(vv) : "memory"); \
      } \
    } \
    if ((t) < T_ - 1) { pxz = z4; pxr = z4; pxh = z4; XMFMA(XCN); } \
  } while (0)

  for (int t = 0; t < T_; t += 2) {
    ONESTEP(t,     xaA, xaB);   // consume x(t+1), load x(t+2)
    ONESTEP(t + 1, xaB, xaA);   // consume x(t+2), load x(t+3)
  }
#undef ONESTEP
#undef XMFMA
#undef XLOAD
}

// ---------------- fallback scan (round-4, proven) ----------------

template<bool XBQ>
__global__ __launch_bounds__(64, 1) void k_scan_fb(
    const void* __restrict__ xsrc, const float* __restrict__ bias,
    const float* __restrict__ pp, const float* __restrict__ h0,
    const u16* __restrict__ WrT, const u16* __restrict__ WxT,
    u16* __restrict__ hbuf, u32* __restrict__ cnt, float* __restrict__ out)
{
  __shared__ short8 lB[4608];

  const int tid = threadIdx.x;
  const int g = blockIdx.x & 7;
  const int s = blockIdx.x >> 3;
  const int scol0 = s * 16;

  for (int lin = tid; lin < 3072; lin += 64) {
    int lp = lin & 63, ks = (lin >> 6) & 15, gate = lin >> 10;
    int cc = lp & 15, kk = lp >> 4;
    lB[lin] = *(const short8*)(WrT + (size_t)(gate * U_ + scol0 + cc) * U_ + ks * 32 + kk * 8);
  }
  for (int lin = tid; lin < 1536; lin += 64) {
    int lp = lin & 63, ks = (lin >> 6) & 7, gate = lin >> 9;
    int cc = lp & 15, kk = lp >> 4;
    lB[3072 + lin] = *(const short8*)(WxT + (size_t)(gate * U_ + scol0 + cc) * IND_ + ks * 32 + kk * 8);
  }
  __syncthreads();

  const int c = tid & 15, kg = tid >> 4;
  const int col = scol0 + c;
  const int kge = kg & 1;

  float bpz[4], bpr[4], pph[4], hprev[4];
  float bh = bias[2 * U_ + col];
#pragma unroll
  for (int q = 0; q < 4; ++q) {
    int bg = g * BPG + kge * 4 + q;
    bpz[q]   = bias[col]       + pp[(size_t)bg * G3_ + col];
    bpr[q]   = bias[U_ + col]  + pp[(size_t)bg * G3_ + U_ + col];
    pph[q]   = pp[(size_t)bg * G3_ + 2 * U_ + col];
    hprev[q] = h0[(size_t)bg * U_ + col];
  }

  u16* hbA = hbuf + (size_t)(g * 2 + 0) * BPG * U_;
  u16* hbB = hbuf + (size_t)(g * 2 + 1) * BPG * U_;
  u32* cntp  = cnt + g * 32;
  u32* flags = cnt + 256 + g * 64;
  const u32* fp = flags + (tid & 31);

#pragma unroll
  for (int q = 0; q < 4; ++q) {
    u32 hv = (u32)f2b(hprev[q]);
    u32 ov = (u32)__shfl_xor((int)hv, 1);
    if (kg < 2 && !(c & 1))
      __hip_atomic_store((u32*)(hbA + (size_t)(kg * 4 + q) * U_ + col), hv | (ov << 16),
                         __ATOMIC_RELAXED, __HIP_MEMORY_SCOPE_AGENT);
  }
  drain_vm();
  if (tid == 0)
    __hip_atomic_fetch_add(cntp, 1u, __ATOMIC_RELAXED, __HIP_MEMORY_SCOPE_AGENT);

  const u16*   xbrow = (const u16*)xsrc   + (size_t)(g * BPG + (c & 7)) * T_ * IND_;
  const float* xfrow = (const float*)xsrc + (size_t)(g * BPG + (c & 7)) * T_ * IND_;
  const f32x4 z4 = {0.f, 0.f, 0.f, 0.f};
  f32x4 pxz = z4, pxr = z4, pxh = z4;

#define GEMM_XFB(tt, AZ, AR, AH) do { \
    _Pragma("unroll") \
    for (int ks = 0; ks < 8; ++ks) { \
      S8 a_; \
      if constexpr (XBQ) { \
        a_.v = *(const short8*)(xbrow + (size_t)(tt) * IND_ + kg * 8 + ks * 32); \
      } else { \
        const float4* p4_ = (const float4*)(xfrow + (size_t)(tt) * IND_ + kg * 8 + ks * 32); \
        float4 x0_ = p4_[0], x1_ = p4_[1]; \
        a_.us[0]=f2b(x0_.x); a_.us[1]=f2b(x0_.y); a_.us[2]=f2b(x0_.z); a_.us[3]=f2b(x0_.w); \
        a_.us[4]=f2b(x1_.x); a_.us[5]=f2b(x1_.y); a_.us[6]=f2b(x1_.z); a_.us[7]=f2b(x1_.w); \
      } \
      AZ = __builtin_amdgcn_mfma_f32_16x16x32_bf16(a_.v, lB[3072 + (0*8+ks)*64 + tid], AZ, 0,0,0); \
      AR = __builtin_amdgcn_mfma_f32_16x16x32_bf16(a_.v, lB[3072 + (1*8+ks)*64 + tid], AR, 0,0,0); \
      AH = __builtin_amdgcn_mfma_f32_16x16x32_bf16(a_.v, lB[3072 + (2*8+ks)*64 + tid], AH, 0,0,0); \
    } \
  } while (0)

  GEMM_XFB(0, pxz, pxr, pxh);

  while (__hip_atomic_load(cntp, __ATOMIC_RELAXED, __HIP_MEMORY_SCOPE_AGENT) < (u32)SLOTS)
    __builtin_amdgcn_s_sleep(1);

  for (int t = 0; t < T_; ++t) {
    const u16* hb = ((t & 1) ? hbB : hbA) + (size_t)(c & 7) * U_ + kg * 8;
    S8 aa[16];
    LDA16(aa, hb);

    f32x4 az = pxz, ar = pxr, ah = pxh, ahr = z4;
#pragma unroll
    for (int ks = 0; ks < 16; ++ks) {
      az  = __builtin_amdgcn_mfma_f32_16x16x32_bf16(aa[ks].v, lB[(0*16+ks)*64 + tid], az,  0,0,0);
      ar  = __builtin_amdgcn_mfma_f32_16x16x32_bf16(aa[ks].v, lB[(1*16+ks)*64 + tid], ar,  0,0,0);
      ahr = __builtin_amdgcn_mfma_f32_16x16x32_bf16(aa[ks].v, lB[(2*16+ks)*64 + tid], ahr, 0,0,0);
    }

    float hnew[4];
#pragma unroll
    for (int q = 0; q < 4; ++q) {
      float z = hsig(az[q] + bpz[q]);
      float r = hsig(ar[q] + bpr[q]);
      float hh = fast_tanh(ah[q] + bh + r * (ahr[q] + pph[q]));
      hnew[q] = fmaf(z, hprev[q] - hh, hh);
      hprev[q] = hnew[q];
    }

    u16* ho = (t & 1) ? hbA : hbB;
#pragma unroll
    for (int q = 0; q < 4; ++q) {
      u32 hv = (u32)f2b(hnew[q]);
      u32 ov = (u32)__shfl_xor((int)hv, 1);
      if (kg < 2 && !(c & 1))
        __hip_atomic_store((u32*)(ho + (size_t)(kg * 4 + q) * U_ + col), hv | (ov << 16),
                           __ATOMIC_RELAXED, __HIP_MEMORY_SCOPE_AGENT);
    }
    drain_vm();
    if (tid == 0) st_sys((u32*)(flags + s), (u32)(t + 1));

    if (t < T_ - 1) {
      pxz = z4; pxr = z4; pxh = z4;
      GEMM_XFB(t + 1, pxz, pxr, pxh);
    }
    if (kg < 2) {
#pragma unroll
      for (int q = 0; q < 4; ++q) {
        int bg = g * BPG + kg * 4 + q;
        out[((size_t)bg * T_ + t) * U_ + col] = hnew[q];
      }
    }
    if (t < T_ - 1) {
      u32 target = (u32)(t + 1);
      while (true) {
        u32 v = ld_sys(fp);
        if (__all((int)(v >= target))) break;
        __builtin_amdgcn_s_sleep(1);
      }
    }
  }
#undef GEMM_XFB
}

// ---------------- launch ----------------

extern "C" void kernel_launch(void* const* d_in, const int* in_sizes, int n_in,
                              void* d_out, int out_size, void* d_ws, size_t ws_size,
                              hipStream_t stream) {
  const float* x    = (const float*)d_in[0];
  const float* peak = (const float*)d_in[1];
  const float* xk   = (const float*)d_in[2];
  const float* rk   = (const float*)d_in[3];
  const float* pk   = (const float*)d_in[4];
  const float* bias = (const float*)d_in[5];
  const float* pi   = (const float*)d_in[6];
  float* out = (float*)d_out;

  char* w = (char*)d_ws;
  u16*   WrT = (u16*)(w);               // 1,572,864 B  [1536][512] bf16
  u16*   WxT = (u16*)(w + 1572864);     //   786,432 B  [1536][256] bf16
  float* pp  = (float*)(w + 2359296);   //   393,216 B  (ends 2,752,512)

  const size_t HBUF_BYTES = (size_t)(T_ + 1) * B_ * U_ * 2;   // 67,174,400
  const size_t NEED_S_F32 = (size_t)2752512 + HBUF_BYTES;     //  69,926,912
  const size_t NEED_S_XB  = NEED_S_F32 + 33554432;            // 103,481,344
  const size_t NEED_FB_XB = (size_t)36573184;

  k_wt<<<dim3(4608), dim3(256), 0, stream>>>(rk, xk, WrT, WxT);
  k_pp<<<dim3(384),  dim3(256), 0, stream>>>(peak, pk, pp);

  if (ws_size >= NEED_S_F32) {
    u16* hbuf = (u16*)(w + 2752512);                 // 67,174,400 B
    k_fill<<<dim3(16400), dim3(256), 0, stream>>>((u32x4*)hbuf);
    k_h0b <<<dim3(128),   dim3(256), 0, stream>>>(peak, pi, hbuf);   // slice 0
    if (ws_size >= NEED_S_XB) {
      u16* xb = (u16*)(w + 69926912);                // 33,554,432 B
      k_xb<<<dim3(8192), dim3(256), 0, stream>>>(x, xb);
      k_scan_s<true><<<dim3(128), dim3(64), 0, stream>>>(xb, bias, pp, WrT, WxT, hbuf);
    } else {
      k_scan_s<false><<<dim3(128), dim3(64), 0, stream>>>(x, bias, pp, WrT, WxT, hbuf);
    }
    k_out<<<dim3(16384), dim3(256), 0, stream>>>(hbuf, out);
  } else {
    float* h0   = (float*)(w + 2752512);   //   131,072 B
    u16*   hbuf = (u16*)(w + 2883584);     //   131,072 B (2-parity)
    u32*   cnt  = (u32*)(w + 3014656);     //     4,096 B
    k_zero<<<dim3(1),   dim3(256), 0, stream>>>(cnt);
    k_h0  <<<dim3(128), dim3(256), 0, stream>>>(peak, pi, h0, hbuf);
    if (ws_size >= NEED_FB_XB) {
      u16* xb = (u16*)(w + 3018752);
      k_xb<<<dim3(8192), dim3(256), 0, stream>>>(x, xb);
      k_scan_fb<true><<<dim3(256), dim3(64), 0, stream>>>(xb, bias, pp, h0, WrT, WxT, hbuf, cnt, out);
    } else {
      k_scan_fb<false><<<dim3(256), dim3(64), 0, stream>>>(x, bias, pp, h0, WrT, WxT, hbuf, cnt, out);
    }
  }
}

// Round 14
// 2900.769 us; speedup vs baseline: 1.0920x; 1.0920x over previous
//
#include <hip/hip_runtime.h>
#include <hip/hip_bf16.h>

#define B_   64
#define T_   1024
#define IND_ 256
#define U_   512
#define G3_  1536
#define BPG   8     // fallback: batches per group
#define SLOTS 32    // fallback: WGs per group

typedef unsigned int u32;
typedef unsigned short u16;
typedef unsigned long long u64;
typedef __attribute__((ext_vector_type(8))) short short8;
typedef __attribute__((ext_vector_type(4))) float f32x4;
typedef __attribute__((ext_vector_type(4))) unsigned int u32x4;

union S8 { short8 v; u16 us[8]; u32 d[4]; u64 q[2]; };
union BF { __hip_bfloat16 b; u16 u; };
union FU { float f; u32 u; };

__device__ __forceinline__ u16 f2b(float f){ BF t; t.b = __float2bfloat16(f); return t.u; }
__device__ __forceinline__ float b2f(u16 u){ FU t; t.u = ((u32)u) << 16; return t.f; }
__device__ __forceinline__ float hsig(float a){ return fminf(fmaxf(fmaf(a, 0.2f, 0.5f), 0.f), 1.f); }
__device__ __forceinline__ u32 umax2(u32 a, u32 b){ return a > b ? a : b; }
__device__ __forceinline__ float fast_tanh(float x){
  float ax = fabsf(x);
  float e  = __expf(ax + ax);
  float r  = 1.f - 2.f / (e + 1.f);
  return copysignf(r, x);
}
__device__ __forceinline__ void drain_vm(){
  asm volatile("s_waitcnt vmcnt(0)" ::: "memory");
  __builtin_amdgcn_sched_barrier(0);
}
__device__ __forceinline__ void st_sys(u32* p, u32 v){
  asm volatile("global_store_dword %0, %1, off sc0 sc1" :: "v"(p), "v"(v) : "memory");
}
__device__ __forceinline__ u32 ld_sys(const u32* p){
  u32 v;
  asm volatile("global_load_dword %0, %1, off sc0 sc1\n\ts_waitcnt vmcnt(0)"
               : "=v"(v) : "v"(p) : "memory");
  return v;
}

// batched A-fragment load: 16 x 16B, device-coherent, ONE wait
#define LDA16(aa, hb) \
  asm volatile( \
    "global_load_dwordx4 %0,  %16, off sc0 sc1\n\t" \
    "global_load_dwordx4 %1,  %16, off offset:64 sc0 sc1\n\t" \
    "global_load_dwordx4 %2,  %16, off offset:128 sc0 sc1\n\t" \
    "global_load_dwordx4 %3,  %16, off offset:192 sc0 sc1\n\t" \
    "global_load_dwordx4 %4,  %16, off offset:256 sc0 sc1\n\t" \
    "global_load_dwordx4 %5,  %16, off offset:320 sc0 sc1\n\t" \
    "global_load_dwordx4 %6,  %16, off offset:384 sc0 sc1\n\t" \
    "global_load_dwordx4 %7,  %16, off offset:448 sc0 sc1\n\t" \
    "global_load_dwordx4 %8,  %16, off offset:512 sc0 sc1\n\t" \
    "global_load_dwordx4 %9,  %16, off offset:576 sc0 sc1\n\t" \
    "global_load_dwordx4 %10, %16, off offset:640 sc0 sc1\n\t" \
    "global_load_dwordx4 %11, %16, off offset:704 sc0 sc1\n\t" \
    "global_load_dwordx4 %12, %16, off offset:768 sc0 sc1\n\t" \
    "global_load_dwordx4 %13, %16, off offset:832 sc0 sc1\n\t" \
    "global_load_dwordx4 %14, %16, off offset:896 sc0 sc1\n\t" \
    "global_load_dwordx4 %15, %16, off offset:960 sc0 sc1\n\t" \
    "s_waitcnt vmcnt(0)" \
    : "=&v"(aa[0].v),  "=&v"(aa[1].v),  "=&v"(aa[2].v),  "=&v"(aa[3].v), \
      "=&v"(aa[4].v),  "=&v"(aa[5].v),  "=&v"(aa[6].v),  "=&v"(aa[7].v), \
      "=&v"(aa[8].v),  "=&v"(aa[9].v),  "=&v"(aa[10].v), "=&v"(aa[11].v), \
      "=&v"(aa[12].v), "=&v"(aa[13].v), "=&v"(aa[14].v), "=&v"(aa[15].v) \
    : "v"(hb) : "memory")

// ---------------- prep kernels ----------------

__global__ void k_zero(u32* c) {
  int i = threadIdx.x;
  for (int k = i; k < 1024; k += 256) c[k] = 0u;
}

__global__ void k_fill(u32x4* p) {   // sentinel fill
  size_t i = (size_t)blockIdx.x * 256 + threadIdx.x;
  u32x4 v = {0xFFFFFFFFu, 0xFFFFFFFFu, 0xFFFFFFFFu, 0xFFFFFFFFu};
  p[i] = v;
}

__global__ void k_wt(const float* __restrict__ rk, const float* __restrict__ xk,
                     u16* __restrict__ WrT, u16* __restrict__ WxT) {
  int i = blockIdx.x * 256 + threadIdx.x;
  if (i < U_ * G3_) {
    int k = i / G3_, c = i - k * G3_;
    WrT[(size_t)c * U_ + k] = f2b(rk[i]);
  } else {
    int j = i - U_ * G3_;
    int k = j / G3_, c = j - k * G3_;
    WxT[(size_t)c * IND_ + k] = f2b(xk[j]);
  }
}

__global__ void k_xb(const float* __restrict__ x, u16* __restrict__ xb) {
  size_t i = ((size_t)blockIdx.x * 256 + threadIdx.x) * 8;
  const float4* p = (const float4*)(x + i);
  float4 a = p[0], b = p[1];
  S8 o;
  o.us[0]=f2b(a.x); o.us[1]=f2b(a.y); o.us[2]=f2b(a.z); o.us[3]=f2b(a.w);
  o.us[4]=f2b(b.x); o.us[5]=f2b(b.y); o.us[6]=f2b(b.z); o.us[7]=f2b(b.w);
  *(short8*)(xb + i) = o.v;
}

__global__ void k_pp(const float* __restrict__ peak, const float* __restrict__ pk,
                     float* __restrict__ pp) {
  int i = blockIdx.x * 256 + threadIdx.x;   // 64*1536
  int b = i / G3_, c = i - b * G3_;
  const float* pr = peak + b * U_;
  float s = 0.f;
  for (int k = 0; k < U_; ++k) s = fmaf(pr[k], pk[(size_t)k * G3_ + c], s);
  pp[i] = s;
}

// primary: h0 -> bf16 directly into hbuf slice 0
__global__ void k_h0b(const float* __restrict__ peak, const float* __restrict__ pi,
                      u16* __restrict__ hb0) {
  int i = blockIdx.x * 256 + threadIdx.x;   // 64*512
  int b = i >> 9, u = i & 511;
  const float* pr = peak + b * U_;
  float s = 0.f;
  for (int k = 0; k < U_; ++k) s = fmaf(pr[k], pi[(size_t)k * U_ + u], s);
  hb0[i] = f2b(s);
}

// fallback: f32 h0 + bf16 copy
__global__ void k_h0(const float* __restrict__ peak, const float* __restrict__ pi,
                     float* __restrict__ h0, u16* __restrict__ hb0) {
  int i = blockIdx.x * 256 + threadIdx.x;
  int b = i >> 9, u = i & 511;
  const float* pr = peak + b * U_;
  float s = 0.f;
  for (int k = 0; k < U_; ++k) s = fmaf(pr[k], pi[(size_t)k * U_ + u], s);
  h0[i] = s;
  hb0[i] = f2b(s);
}

// out[b][t][u] = f32(hbuf[t+1][b][u]) — pure bandwidth
__global__ void k_out(const u16* __restrict__ hbuf, float* __restrict__ out) {
  size_t i = ((size_t)blockIdx.x * 256 + threadIdx.x) * 8;   // out linear idx
  size_t b = i >> 19;
  size_t r = i & 524287;
  size_t t = r >> 9;
  size_t u = r & 511;
  S8 v;
  v.v = *(const short8*)(hbuf + (t + 1) * (size_t)(B_ * U_) + b * U_ + u);
  float4 o0, o1;
  o0.x = b2f(v.us[0]); o0.y = b2f(v.us[1]); o0.z = b2f(v.us[2]); o0.w = b2f(v.us[3]);
  o1.x = b2f(v.us[4]); o1.y = b2f(v.us[5]); o1.z = b2f(v.us[6]); o1.w = b2f(v.us[7]);
  float4* dst = (float4*)(out + i);
  dst[0] = o0;
  dst[1] = o1;
}

// ---------------- SENT scan: sentinel dataflow (round-10 protocol, verbatim) ----------------
// 128 one-wave WGs. Group g = bid&3 owns batches [16g,16g+16); slot s = bid>>2
// owns h-columns [16s,16s+16). hbuf = [1025][64][512] bf16 sentinel-prefilled.
// Consumers poll the data itself (retry while any sentinel dword); producers
// fire-and-forget dword stores. No out stores in the loop (k_out converts
// hbuf afterwards). NO prefetch of future slices: touching a line before its
// producer writes it corrupts the protocol (r12/r13 NaN — rule locked in).

template<bool XBQ>
__global__ __launch_bounds__(64, 1) void k_scan_s(
    const void* __restrict__ xsrc, const float* __restrict__ bias,
    const float* __restrict__ pp,
    const u16* __restrict__ WrT, const u16* __restrict__ WxT,
    u16* __restrict__ hbuf)
{
  __shared__ short8 lB[4608];   // [0,3072): Wr frag-linear; [3072,4608): Wx

  const int tid = threadIdx.x;
  const int g = blockIdx.x & 3;
  const int s = blockIdx.x >> 2;
  const int scol0 = s * 16;

  for (int lin = tid; lin < 3072; lin += 64) {
    int lp = lin & 63, ks = (lin >> 6) & 15, gate = lin >> 10;
    int cc = lp & 15, kk = lp >> 4;
    lB[lin] = *(const short8*)(WrT + (size_t)(gate * U_ + scol0 + cc) * U_ + ks * 32 + kk * 8);
  }
  for (int lin = tid; lin < 1536; lin += 64) {
    int lp = lin & 63, ks = (lin >> 6) & 7, gate = lin >> 9;
    int cc = lp & 15, kk = lp >> 4;
    lB[3072 + lin] = *(const short8*)(WxT + (size_t)(gate * U_ + scol0 + cc) * IND_ + ks * 32 + kk * 8);
  }
  __syncthreads();

  const int c   = tid & 15;
  const int kg  = tid >> 4;
  const int col = scol0 + c;

  float bpz[4], bpr[4], pph[4], hprev[4];
  float bh = bias[2 * U_ + col];
#pragma unroll
  for (int q = 0; q < 4; ++q) {
    int bg = g * 16 + kg * 4 + q;
    bpz[q]   = bias[col]       + pp[(size_t)bg * G3_ + col];
    bpr[q]   = bias[U_ + col]  + pp[(size_t)bg * G3_ + U_ + col];
    pph[q]   = pp[(size_t)bg * G3_ + 2 * U_ + col];
    hprev[q] = b2f(hbuf[(size_t)bg * U_ + col]);   // slice 0 = h0 (bf16)
  }

  const u16*   xbrow = (const u16*)xsrc   + (size_t)(g * 16 + c) * T_ * IND_;
  const float* xfrow = (const float*)xsrc + (size_t)(g * 16 + c) * T_ * IND_;
  const f32x4 z4 = {0.f, 0.f, 0.f, 0.f};
  f32x4 pxz, pxr, pxh;
  S8 xaA[8], xaB[8];

#define XLOAD(tt, XA) do { \
    if constexpr (XBQ) { \
      _Pragma("unroll") \
      for (int ks = 0; ks < 8; ++ks) \
        XA[ks].v = *(const short8*)(xbrow + (size_t)(tt) * IND_ + kg * 8 + ks * 32); \
    } else { \
      _Pragma("unroll") \
      for (int ks = 0; ks < 8; ++ks) { \
        const float4* p4_ = (const float4*)(xfrow + (size_t)(tt) * IND_ + kg * 8 + ks * 32); \
        float4 x0_ = p4_[0], x1_ = p4_[1]; \
        XA[ks].us[0]=f2b(x0_.x); XA[ks].us[1]=f2b(x0_.y); XA[ks].us[2]=f2b(x0_.z); XA[ks].us[3]=f2b(x0_.w); \
        XA[ks].us[4]=f2b(x1_.x); XA[ks].us[5]=f2b(x1_.y); XA[ks].us[6]=f2b(x1_.z); XA[ks].us[7]=f2b(x1_.w); \
      } \
    } \
  } while (0)

#define XMFMA(XA) do { \
    _Pragma("unroll") \
    for (int ks = 0; ks < 8; ++ks) { \
      pxz = __builtin_amdgcn_mfma_f32_16x16x32_bf16(XA[ks].v, lB[3072 + (0*8+ks)*64 + tid], pxz, 0,0,0); \
      pxr = __builtin_amdgcn_mfma_f32_16x16x32_bf16(XA[ks].v, lB[3072 + (1*8+ks)*64 + tid], pxr, 0,0,0); \
      pxh = __builtin_amdgcn_mfma_f32_16x16x32_bf16(XA[ks].v, lB[3072 + (2*8+ks)*64 + tid], pxh, 0,0,0); \
    } \
  } while (0)

  // prologue: XGEMM(0) ready before first poll; x(1) in flight in xaA
  XLOAD(0, xaB);
  pxz = z4; pxr = z4; pxh = z4;
  XMFMA(xaB);
  XLOAD(1, xaA);

// one timestep. XCN = x(t+1) regs (consumed by XMFMA at end);
// XLD = buffer receiving x(t+2) (issued right after poll success).
#define ONESTEP(t, XCN, XLD) do { \
    const u16* hb = hbuf + (size_t)(t) * (B_ * U_) + (size_t)(g * 16 + c) * U_ + kg * 8; \
    S8 aa[16]; \
    for (;;) { \
      LDA16(aa, hb); \
      u32 mx = 0; \
      _Pragma("unroll") \
      for (int ks = 0; ks < 16; ++ks) \
        mx = umax2(mx, umax2(umax2(aa[ks].d[0], aa[ks].d[1]), \
                             umax2(aa[ks].d[2], aa[ks].d[3]))); \
      if (__all((int)(mx < 0xFFFF0000u))) break; \
    } \
    if ((t) + 2 < T_) XLOAD((t) + 2, XLD);          /* ~1.5 steps of flight */ \
    f32x4 az = pxz, ar = pxr, ah = pxh, ahr = z4; \
    _Pragma("unroll") \
    for (int ks = 0; ks < 16; ++ks) { \
      az  = __builtin_amdgcn_mfma_f32_16x16x32_bf16(aa[ks].v, lB[(0*16+ks)*64 + tid], az,  0,0,0); \
      ar  = __builtin_amdgcn_mfma_f32_16x16x32_bf16(aa[ks].v, lB[(1*16+ks)*64 + tid], ar,  0,0,0); \
      ahr = __builtin_amdgcn_mfma_f32_16x16x32_bf16(aa[ks].v, lB[(2*16+ks)*64 + tid], ahr, 0,0,0); \
    } \
    float hnew[4]; \
    _Pragma("unroll") \
    for (int q = 0; q < 4; ++q) { \
      float z  = hsig(az[q] + bpz[q]); \
      float r  = hsig(ar[q] + bpr[q]); \
      float hh = fast_tanh(ah[q] + bh + r * (ahr[q] + pph[q])); \
      hnew[q] = fmaf(z, hprev[q] - hh, hh); \
      hprev[q] = hnew[q]; \
    } \
    u16* hb1 = hbuf + (size_t)((t) + 1) * (B_ * U_); \
    _Pragma("unroll") \
    for (int q = 0; q < 4; ++q) { \
      u32 hv = (u32)f2b(hnew[q]); \
      u32 ov = (u32)__shfl_xor((int)hv, 1); \
      if (!(c & 1)) \
        st_sys((u32*)(hb1 + (size_t)(g * 16 + kg * 4 + q) * U_ + col), hv | (ov << 16)); \
    } \
    if ((t) < T_ - 1) { pxz = z4; pxr = z4; pxh = z4; XMFMA(XCN); } \
  } while (0)

  for (int t = 0; t < T_; t += 2) {
    ONESTEP(t,     xaA, xaB);   // consume x(t+1), load x(t+2)
    ONESTEP(t + 1, xaB, xaA);   // consume x(t+2), load x(t+3)
  }
#undef ONESTEP
#undef XMFMA
#undef XLOAD
}

// ---------------- fallback scan (round-4, proven) ----------------

template<bool XBQ>
__global__ __launch_bounds__(64, 1) void k_scan_fb(
    const void* __restrict__ xsrc, const float* __restrict__ bias,
    const float* __restrict__ pp, const float* __restrict__ h0,
    const u16* __restrict__ WrT, const u16* __restrict__ WxT,
    u16* __restrict__ hbuf, u32* __restrict__ cnt, float* __restrict__ out)
{
  __shared__ short8 lB[4608];

  const int tid = threadIdx.x;
  const int g = blockIdx.x & 7;
  const int s = blockIdx.x >> 3;
  const int scol0 = s * 16;

  for (int lin = tid; lin < 3072; lin += 64) {
    int lp = lin & 63, ks = (lin >> 6) & 15, gate = lin >> 10;
    int cc = lp & 15, kk = lp >> 4;
    lB[lin] = *(const short8*)(WrT + (size_t)(gate * U_ + scol0 + cc) * U_ + ks * 32 + kk * 8);
  }
  for (int lin = tid; lin < 1536; lin += 64) {
    int lp = lin & 63, ks = (lin >> 6) & 7, gate = lin >> 9;
    int cc = lp & 15, kk = lp >> 4;
    lB[3072 + lin] = *(const short8*)(WxT + (size_t)(gate * U_ + scol0 + cc) * IND_ + ks * 32 + kk * 8);
  }
  __syncthreads();

  const int c = tid & 15, kg = tid >> 4;
  const int col = scol0 + c;
  const int kge = kg & 1;

  float bpz[4], bpr[4], pph[4], hprev[4];
  float bh = bias[2 * U_ + col];
#pragma unroll
  for (int q = 0; q < 4; ++q) {
    int bg = g * BPG + kge * 4 + q;
    bpz[q]   = bias[col]       + pp[(size_t)bg * G3_ + col];
    bpr[q]   = bias[U_ + col]  + pp[(size_t)bg * G3_ + U_ + col];
    pph[q]   = pp[(size_t)bg * G3_ + 2 * U_ + col];
    hprev[q] = h0[(size_t)bg * U_ + col];
  }

  u16* hbA = hbuf + (size_t)(g * 2 + 0) * BPG * U_;
  u16* hbB = hbuf + (size_t)(g * 2 + 1) * BPG * U_;
  u32* cntp  = cnt + g * 32;
  u32* flags = cnt + 256 + g * 64;
  const u32* fp = flags + (tid & 31);

#pragma unroll
  for (int q = 0; q < 4; ++q) {
    u32 hv = (u32)f2b(hprev[q]);
    u32 ov = (u32)__shfl_xor((int)hv, 1);
    if (kg < 2 && !(c & 1))
      __hip_atomic_store((u32*)(hbA + (size_t)(kg * 4 + q) * U_ + col), hv | (ov << 16),
                         __ATOMIC_RELAXED, __HIP_MEMORY_SCOPE_AGENT);
  }
  drain_vm();
  if (tid == 0)
    __hip_atomic_fetch_add(cntp, 1u, __ATOMIC_RELAXED, __HIP_MEMORY_SCOPE_AGENT);

  const u16*   xbrow = (const u16*)xsrc   + (size_t)(g * BPG + (c & 7)) * T_ * IND_;
  const float* xfrow = (const float*)xsrc + (size_t)(g * BPG + (c & 7)) * T_ * IND_;
  const f32x4 z4 = {0.f, 0.f, 0.f, 0.f};
  f32x4 pxz = z4, pxr = z4, pxh = z4;

#define GEMM_XFB(tt, AZ, AR, AH) do { \
    _Pragma("unroll") \
    for (int ks = 0; ks < 8; ++ks) { \
      S8 a_; \
      if constexpr (XBQ) { \
        a_.v = *(const short8*)(xbrow + (size_t)(tt) * IND_ + kg * 8 + ks * 32); \
      } else { \
        const float4* p4_ = (const float4*)(xfrow + (size_t)(tt) * IND_ + kg * 8 + ks * 32); \
        float4 x0_ = p4_[0], x1_ = p4_[1]; \
        a_.us[0]=f2b(x0_.x); a_.us[1]=f2b(x0_.y); a_.us[2]=f2b(x0_.z); a_.us[3]=f2b(x0_.w); \
        a_.us[4]=f2b(x1_.x); a_.us[5]=f2b(x1_.y); a_.us[6]=f2b(x1_.z); a_.us[7]=f2b(x1_.w); \
      } \
      AZ = __builtin_amdgcn_mfma_f32_16x16x32_bf16(a_.v, lB[3072 + (0*8+ks)*64 + tid], AZ, 0,0,0); \
      AR = __builtin_amdgcn_mfma_f32_16x16x32_bf16(a_.v, lB[3072 + (1*8+ks)*64 + tid], AR, 0,0,0); \
      AH = __builtin_amdgcn_mfma_f32_16x16x32_bf16(a_.v, lB[3072 + (2*8+ks)*64 + tid], AH, 0,0,0); \
    } \
  } while (0)

  GEMM_XFB(0, pxz, pxr, pxh);

  while (__hip_atomic_load(cntp, __ATOMIC_RELAXED, __HIP_MEMORY_SCOPE_AGENT) < (u32)SLOTS)
    __builtin_amdgcn_s_sleep(1);

  for (int t = 0; t < T_; ++t) {
    const u16* hb = ((t & 1) ? hbB : hbA) + (size_t)(c & 7) * U_ + kg * 8;
    S8 aa[16];
    LDA16(aa, hb);

    f32x4 az = pxz, ar = pxr, ah = pxh, ahr = z4;
#pragma unroll
    for (int ks = 0; ks < 16; ++ks) {
      az  = __builtin_amdgcn_mfma_f32_16x16x32_bf16(aa[ks].v, lB[(0*16+ks)*64 + tid], az,  0,0,0);
      ar  = __builtin_amdgcn_mfma_f32_16x16x32_bf16(aa[ks].v, lB[(1*16+ks)*64 + tid], ar,  0,0,0);
      ahr = __builtin_amdgcn_mfma_f32_16x16x32_bf16(aa[ks].v, lB[(2*16+ks)*64 + tid], ahr, 0,0,0);
    }

    float hnew[4];
#pragma unroll
    for (int q = 0; q < 4; ++q) {
      float z = hsig(az[q] + bpz[q]);
      float r = hsig(ar[q] + bpr[q]);
      float hh = fast_tanh(ah[q] + bh + r * (ahr[q] + pph[q]));
      hnew[q] = fmaf(z, hprev[q] - hh, hh);
      hprev[q] = hnew[q];
    }

    u16* ho = (t & 1) ? hbA : hbB;
#pragma unroll
    for (int q = 0; q < 4; ++q) {
      u32 hv = (u32)f2b(hnew[q]);
      u32 ov = (u32)__shfl_xor((int)hv, 1);
      if (kg < 2 && !(c & 1))
        __hip_atomic_store((u32*)(ho + (size_t)(kg * 4 + q) * U_ + col), hv | (ov << 16),
                           __ATOMIC_RELAXED, __HIP_MEMORY_SCOPE_AGENT);
    }
    drain_vm();
    if (tid == 0) st_sys((u32*)(flags + s), (u32)(t + 1));

    if (t < T_ - 1) {
      pxz = z4; pxr = z4; pxh = z4;
      GEMM_XFB(t + 1, pxz, pxr, pxh);
    }
    if (kg < 2) {
#pragma unroll
      for (int q = 0; q < 4; ++q) {
        int bg = g * BPG + kg * 4 + q;
        out[((size_t)bg * T_ + t) * U_ + col] = hnew[q];
      }
    }
    if (t < T_ - 1) {
      u32 target = (u32)(t + 1);
      while (true) {
        u32 v = ld_sys(fp);
        if (__all((int)(v >= target))) break;
        __builtin_amdgcn_s_sleep(1);
      }
    }
  }
#undef GEMM_XFB
}

// ---------------- launch ----------------

extern "C" void kernel_launch(void* const* d_in, const int* in_sizes, int n_in,
                              void* d_out, int out_size, void* d_ws, size_t ws_size,
                              hipStream_t stream) {
  const float* x    = (const float*)d_in[0];
  const float* peak = (const float*)d_in[1];
  const float* xk   = (const float*)d_in[2];
  const float* rk   = (const float*)d_in[3];
  const float* pk   = (const float*)d_in[4];
  const float* bias = (const float*)d_in[5];
  const float* pi   = (const float*)d_in[6];
  float* out = (float*)d_out;

  char* w = (char*)d_ws;
  u16*   WrT = (u16*)(w);               // 1,572,864 B  [1536][512] bf16
  u16*   WxT = (u16*)(w + 1572864);     //   786,432 B  [1536][256] bf16
  float* pp  = (float*)(w + 2359296);   //   393,216 B  (ends 2,752,512)

  const size_t HBUF_BYTES = (size_t)(T_ + 1) * B_ * U_ * 2;   // 67,174,400
  const size_t NEED_S_F32 = (size_t)2752512 + HBUF_BYTES;     //  69,926,912
  const size_t NEED_S_XB  = NEED_S_F32 + 33554432;            // 103,481,344
  const size_t NEED_FB_XB = (size_t)36573184;

  k_wt<<<dim3(4608), dim3(256), 0, stream>>>(rk, xk, WrT, WxT);
  k_pp<<<dim3(384),  dim3(256), 0, stream>>>(peak, pk, pp);

  if (ws_size >= NEED_S_F32) {
    u16* hbuf = (u16*)(w + 2752512);                 // 67,174,400 B
    k_fill<<<dim3(16400), dim3(256), 0, stream>>>((u32x4*)hbuf);
    k_h0b <<<dim3(128),   dim3(256), 0, stream>>>(peak, pi, hbuf);   // slice 0
    if (ws_size >= NEED_S_XB) {
      u16* xb = (u16*)(w + 69926912);                // 33,554,432 B
      k_xb<<<dim3(8192), dim3(256), 0, stream>>>(x, xb);
      k_scan_s<true><<<dim3(128), dim3(64), 0, stream>>>(xb, bias, pp, WrT, WxT, hbuf);
    } else {
      k_scan_s<false><<<dim3(128), dim3(64), 0, stream>>>(x, bias, pp, WrT, WxT, hbuf);
    }
    k_out<<<dim3(16384), dim3(256), 0, stream>>>(hbuf, out);
  } else {
    float* h0   = (float*)(w + 2752512);   //   131,072 B
    u16*   hbuf = (u16*)(w + 2883584);     //   131,072 B (2-parity)
    u32*   cnt  = (u32*)(w + 3014656);     //     4,096 B
    k_zero<<<dim3(1),   dim3(256), 0, stream>>>(cnt);
    k_h0  <<<dim3(128), dim3(256), 0, stream>>>(peak, pi, h0, hbuf);
    if (ws_size >= NEED_FB_XB) {
      u16* xb = (u16*)(w + 3018752);
      k_xb<<<dim3(8192), dim3(256), 0, stream>>>(x, xb);
      k_scan_fb<true><<<dim3(256), dim3(64), 0, stream>>>(xb, bias, pp, h0, WrT, WxT, hbuf, cnt, out);
    } else {
      k_scan_fb<false><<<dim3(256), dim3(64), 0, stream>>>(x, bias, pp, h0, WrT, WxT, hbuf, cnt, out);
    }
  }
}